// Round 1
// 1133.671 us; speedup vs baseline: 1.1883x; 1.1883x over previous
//
#include <hip/hip_runtime.h>
#include <hip/hip_bf16.h>

#define T 2048
#define H 2560
#define NE 8
#define ITXT 1536
#define IIMG 512
#define ISH 3072
#define CAP 2048

using bf16 = __hip_bfloat16;
typedef short short8 __attribute__((ext_vector_type(8)));
typedef float float4v __attribute__((ext_vector_type(4)));

// ---- workspace layout (bytes) ----
static constexpr size_t OFF_XBF  = 0;                                   // bf16[T*H]
static constexpr size_t OFF_CNT  = OFF_XBF + (size_t)T * H * 2;         // int[32]
static constexpr size_t OFF_TOK  = OFF_CNT + 128;                       // int[17][CAP]
static constexpr size_t OFF_WTS  = OFF_TOK + (size_t)17 * CAP * 4;      // float[17][CAP]
static constexpr size_t OFF_HTXT = OFF_WTS + (size_t)17 * CAP * 4;      // bf16[8][CAP][ITXT]
static constexpr size_t OFF_HIMG = OFF_HTXT + (size_t)NE * CAP * ITXT * 2;
static constexpr size_t OFF_HSH  = OFF_HIMG + (size_t)NE * CAP * IIMG * 2;

__device__ __forceinline__ unsigned short f2bf(float f) {
    bf16 b = __float2bfloat16(f);
    unsigned short u;
    __builtin_memcpy(&u, &b, 2);
    return u;
}

// ---- cast x to bf16 + init shared bucket ----
__global__ void k_cast_init(const float* __restrict__ x, bf16* __restrict__ xb,
                            int* __restrict__ counts, int* __restrict__ toks,
                            float* __restrict__ wts) {
    int i = blockIdx.x * blockDim.x + threadIdx.x;   // < T*H/4
    float4 v = ((const float4*)x)[i];
    ushort4 p;
    p.x = f2bf(v.x); p.y = f2bf(v.y); p.z = f2bf(v.z); p.w = f2bf(v.w);
    *(ushort4*)(xb + 4 * (size_t)i) = p;
    if (i < CAP) { toks[16 * CAP + i] = i; wts[16 * CAP + i] = 1.0f; }
    if (i == 0) counts[16] = T;
}

// ---- router: one wave per token ----
__global__ void k_router(const float* __restrict__ x, const int* __restrict__ vmask,
                         const float* __restrict__ tg, const float* __restrict__ ig,
                         int* __restrict__ counts, int* __restrict__ toks,
                         float* __restrict__ wts) {
    int wave = threadIdx.x >> 6;
    int lane = threadIdx.x & 63;
    int t = blockIdx.x * 4 + wave;
    if (t >= T) return;
    bool vis = vmask[t] != 0;
    const float* gw = vis ? ig : tg;
    const float* xr = x + (size_t)t * H;
    float logits[NE];
#pragma unroll
    for (int e = 0; e < NE; ++e) {
        const float* g = gw + (size_t)e * H;
        double s = 0.0;
        for (int h = lane; h < H; h += 64) s += (double)xr[h] * (double)g[h];
#pragma unroll
        for (int off = 32; off > 0; off >>= 1) s += __shfl_xor(s, off);
        logits[e] = (float)s;
    }
    if (lane == 0) {
        int e1 = 0;
#pragma unroll
        for (int e = 1; e < NE; ++e) if (logits[e] > logits[e1]) e1 = e;
        int e2 = -1;
#pragma unroll
        for (int e = 0; e < NE; ++e)
            if (e != e1 && (e2 < 0 || logits[e] > logits[e2])) e2 = e;
        float w1 = 1.0f / (1.0f + expf(logits[e2] - logits[e1]));
        float w2 = 1.0f - w1;
        int b = vis ? 8 : 0;
        int s1 = atomicAdd(&counts[b + e1], 1);
        toks[(b + e1) * CAP + s1] = t; wts[(b + e1) * CAP + s1] = w1;
        int s2 = atomicAdd(&counts[b + e2], 1);
        toks[(b + e2) * CAP + s2] = t; wts[(b + e2) * CAP + s2] = w2;
    }
}

// ---- grouped GEMM tiles ----
#define MT 128
#define NT 64
#define BK 32
#define LSTR 40   // BK + 8 pad, bf16 elems (row stride 80B, multiple of 16B)

// Fused gate+up for all 17 buckets (8 text, 8 image, 1 shared).
// 2-phase pipeline: reg-staged global loads for tile k+1 issued before MFMA on tile k,
// converted/written to the other LDS buffer after; ONE barrier per K-step.
__global__ __launch_bounds__(256) void k_gateup_all(
    const float* __restrict__ twg, const float* __restrict__ twu,
    const float* __restrict__ iwg, const float* __restrict__ iwu,
    const float* __restrict__ swg, const float* __restrict__ swu,
    const bf16* __restrict__ A,
    const int* __restrict__ counts, const int* __restrict__ toks,
    bf16* __restrict__ htxt, bf16* __restrict__ himg, bf16* __restrict__ hsh) {
    int z = blockIdx.z;
    const float *bg, *bu; int N; bf16* hb;
    if (z < 8) {
        bg = twg + (size_t)z * H * ITXT; bu = twu + (size_t)z * H * ITXT;
        N = ITXT; hb = htxt + (size_t)z * CAP * ITXT;
    } else if (z < 16) {
        int e = z - 8;
        bg = iwg + (size_t)e * H * IIMG; bu = iwu + (size_t)e * H * IIMG;
        N = IIMG; hb = himg + (size_t)e * CAP * IIMG;
    } else {
        bg = swg; bu = swu; N = ISH; hb = hsh;
    }
    int n0 = blockIdx.x * NT;
    if (n0 >= N) return;
    int cnt = counts[z];
    int m0 = blockIdx.y * MT;
    if (m0 >= cnt) return;
    const int* tk = toks + (size_t)z * CAP + m0;

    __shared__ bf16 As[2][MT][LSTR];
    __shared__ bf16 Bs[2][2][NT][LSTR];

    int tid = threadIdx.x;
    int lane = tid & 63;
    int wv = tid >> 6;
    int wm = wv >> 1, wn = wv & 1;

    int ar = tid >> 2;            // A stage: row 0..63 (+64)
    int akc = (tid & 3) << 3;     // k elem offset 0,8,16,24
    int bn = (tid & 15) << 2;     // B stage: n offset
    int bk = (tid >> 4) << 1;     // B stage: k row 0..30
    int fr = lane & 15;           // frag row
    int fk = (lane >> 4) << 3;    // frag k offset

    // hoisted gather: token ids / row pointers fixed across K (clamped to valid rows;
    // garbage rows only affect outputs that are never stored)
    int cl = cnt - m0 - 1;
    int r0 = ar, r1 = ar + 64;
    int t0 = tk[r0 < cl ? r0 : cl];
    int t1 = tk[r1 < cl ? r1 : cl];
    const bf16* aP0 = A + (size_t)t0 * H + akc;
    const bf16* aP1 = A + (size_t)t1 * H + akc;
    const float* pg = bg + (size_t)bk * N + n0 + bn;
    const float* pu = bu + (size_t)bk * N + n0 + bn;

    float4v accg[4][2], accu[4][2];
#pragma unroll
    for (int i = 0; i < 4; ++i)
#pragma unroll
        for (int j = 0; j < 2; ++j) { accg[i][j] = (float4v)0.0f; accu[i][j] = (float4v)0.0f; }

    uint4 a0r, a1r; float4 g0r, g1r, u0r, u1r;
    auto LOADR = [&](int k0) {
        a0r = *(const uint4*)(aP0 + k0);
        a1r = *(const uint4*)(aP1 + k0);
        const float* g = pg + (size_t)k0 * N;
        g0r = *(const float4*)g; g1r = *(const float4*)(g + N);
        const float* u = pu + (size_t)k0 * N;
        u0r = *(const float4*)u; u1r = *(const float4*)(u + N);
    };
    auto STORER = [&](int buf) {
        *(uint4*)&As[buf][ar][akc] = a0r;
        *(uint4*)&As[buf][ar + 64][akc] = a1r;
        *(unsigned*)&Bs[buf][0][bn + 0][bk] = (unsigned)f2bf(g0r.x) | ((unsigned)f2bf(g1r.x) << 16);
        *(unsigned*)&Bs[buf][0][bn + 1][bk] = (unsigned)f2bf(g0r.y) | ((unsigned)f2bf(g1r.y) << 16);
        *(unsigned*)&Bs[buf][0][bn + 2][bk] = (unsigned)f2bf(g0r.z) | ((unsigned)f2bf(g1r.z) << 16);
        *(unsigned*)&Bs[buf][0][bn + 3][bk] = (unsigned)f2bf(g0r.w) | ((unsigned)f2bf(g1r.w) << 16);
        *(unsigned*)&Bs[buf][1][bn + 0][bk] = (unsigned)f2bf(u0r.x) | ((unsigned)f2bf(u1r.x) << 16);
        *(unsigned*)&Bs[buf][1][bn + 1][bk] = (unsigned)f2bf(u0r.y) | ((unsigned)f2bf(u1r.y) << 16);
        *(unsigned*)&Bs[buf][1][bn + 2][bk] = (unsigned)f2bf(u0r.z) | ((unsigned)f2bf(u1r.z) << 16);
        *(unsigned*)&Bs[buf][1][bn + 3][bk] = (unsigned)f2bf(u0r.w) | ((unsigned)f2bf(u1r.w) << 16);
    };

    LOADR(0);
    STORER(0);
    int cur = 0;
    for (int k0 = 0; k0 < H; k0 += BK) {
        __syncthreads();               // LDS[cur] ready for all waves
        bool more = (k0 + BK) < H;
        if (more) LOADR(k0 + BK);      // issue next-tile loads (latency hides under MFMA)
        short8 af[4], bgf[2], buf_[2];
#pragma unroll
        for (int i = 0; i < 4; ++i) af[i] = *(const short8*)&As[cur][wm * 64 + i * 16 + fr][fk];
#pragma unroll
        for (int j = 0; j < 2; ++j) {
            bgf[j]  = *(const short8*)&Bs[cur][0][wn * 32 + j * 16 + fr][fk];
            buf_[j] = *(const short8*)&Bs[cur][1][wn * 32 + j * 16 + fr][fk];
        }
#pragma unroll
        for (int i = 0; i < 4; ++i)
#pragma unroll
            for (int j = 0; j < 2; ++j) {
                accg[i][j] = __builtin_amdgcn_mfma_f32_16x16x32_bf16(af[i], bgf[j],  accg[i][j], 0, 0, 0);
                accu[i][j] = __builtin_amdgcn_mfma_f32_16x16x32_bf16(af[i], buf_[j], accu[i][j], 0, 0, 0);
            }
        if (more) STORER(cur ^ 1);     // vmcnt wait lands here, after MFMA
        cur ^= 1;
    }

    // epilogue: silu(g)*u -> bf16 h
    int rbase = (lane >> 4) << 2;
    int cc = lane & 15;
#pragma unroll
    for (int i = 0; i < 4; ++i)
#pragma unroll
        for (int j = 0; j < 2; ++j)
#pragma unroll
            for (int r = 0; r < 4; ++r) {
                int ml = m0 + wm * 64 + i * 16 + rbase + r;
                if (ml < cnt) {
                    int col = n0 + wn * 32 + j * 16 + cc;
                    float g = accg[i][j][r], u = accu[i][j][r];
                    float hv = g / (1.0f + expf(-g)) * u;
                    hb[(size_t)ml * N + col] = __float2bfloat16(hv);
                }
            }
}

// Fused down-proj for all 17 buckets; same 2-phase pipeline; atomicAdd into out.
__global__ __launch_bounds__(256) void k_down_all(
    const float* __restrict__ twd, const float* __restrict__ iwd, const float* __restrict__ swd,
    const bf16* __restrict__ htxt, const bf16* __restrict__ himg, const bf16* __restrict__ hsh,
    const int* __restrict__ counts, const int* __restrict__ toks,
    const float* __restrict__ wts,
    float* __restrict__ out) {
    int z = blockIdx.z;
    const float* bw; const bf16* Ab; int K;
    if (z < 8) {
        bw = twd + (size_t)z * ITXT * H; Ab = htxt + (size_t)z * CAP * ITXT; K = ITXT;
    } else if (z < 16) {
        int e = z - 8;
        bw = iwd + (size_t)e * IIMG * H; Ab = himg + (size_t)e * CAP * IIMG; K = IIMG;
    } else {
        bw = swd; Ab = hsh; K = ISH;
    }
    int cnt = counts[z];
    int m0 = blockIdx.y * MT;
    if (m0 >= cnt) return;
    int n0 = blockIdx.x * NT;   // N = H always

    __shared__ bf16 As[2][MT][LSTR];
    __shared__ bf16 Bs[2][NT][LSTR];

    int tid = threadIdx.x;
    int lane = tid & 63;
    int wv = tid >> 6;
    int wm = wv >> 1, wn = wv & 1;

    int ar = tid >> 2;
    int akc = (tid & 3) << 3;
    int bn = (tid & 15) << 2;
    int bk = (tid >> 4) << 1;
    int fr = lane & 15;
    int fk = (lane >> 4) << 3;

    // A rows are bucket-local; rows >= cnt read (valid, allocated) garbage that is never stored
    const bf16* aP0 = Ab + (size_t)(m0 + ar) * K + akc;
    const bf16* aP1 = Ab + (size_t)(m0 + ar + 64) * K + akc;
    const float* pb = bw + (size_t)bk * H + n0 + bn;

    float4v acc[4][2];
#pragma unroll
    for (int i = 0; i < 4; ++i)
#pragma unroll
        for (int j = 0; j < 2; ++j) acc[i][j] = (float4v)0.0f;

    uint4 a0r, a1r; float4 b0r, b1r;
    auto LOADR = [&](int k0) {
        a0r = *(const uint4*)(aP0 + k0);
        a1r = *(const uint4*)(aP1 + k0);
        const float* s = pb + (size_t)k0 * H;
        b0r = *(const float4*)s; b1r = *(const float4*)(s + H);
    };
    auto STORER = [&](int buf) {
        *(uint4*)&As[buf][ar][akc] = a0r;
        *(uint4*)&As[buf][ar + 64][akc] = a1r;
        *(unsigned*)&Bs[buf][bn + 0][bk] = (unsigned)f2bf(b0r.x) | ((unsigned)f2bf(b1r.x) << 16);
        *(unsigned*)&Bs[buf][bn + 1][bk] = (unsigned)f2bf(b0r.y) | ((unsigned)f2bf(b1r.y) << 16);
        *(unsigned*)&Bs[buf][bn + 2][bk] = (unsigned)f2bf(b0r.z) | ((unsigned)f2bf(b1r.z) << 16);
        *(unsigned*)&Bs[buf][bn + 3][bk] = (unsigned)f2bf(b0r.w) | ((unsigned)f2bf(b1r.w) << 16);
    };

    LOADR(0);
    STORER(0);
    int cur = 0;
    for (int k0 = 0; k0 < K; k0 += BK) {
        __syncthreads();
        bool more = (k0 + BK) < K;
        if (more) LOADR(k0 + BK);
        short8 af[4], bf_[2];
#pragma unroll
        for (int i = 0; i < 4; ++i) af[i] = *(const short8*)&As[cur][wm * 64 + i * 16 + fr][fk];
#pragma unroll
        for (int j = 0; j < 2; ++j) bf_[j] = *(const short8*)&Bs[cur][wn * 32 + j * 16 + fr][fk];
#pragma unroll
        for (int i = 0; i < 4; ++i)
#pragma unroll
            for (int j = 0; j < 2; ++j)
                acc[i][j] = __builtin_amdgcn_mfma_f32_16x16x32_bf16(af[i], bf_[j], acc[i][j], 0, 0, 0);
        if (more) STORER(cur ^ 1);
        cur ^= 1;
    }

    int rbase = (lane >> 4) << 2;
    int cc = lane & 15;
    const int* tkl = toks + (size_t)z * CAP;
    const float* wl = wts + (size_t)z * CAP;
#pragma unroll
    for (int i = 0; i < 4; ++i)
#pragma unroll
        for (int j = 0; j < 2; ++j)
#pragma unroll
            for (int r = 0; r < 4; ++r) {
                int ml = m0 + wm * 64 + i * 16 + rbase + r;
                if (ml < cnt) {
                    int col = n0 + wn * 32 + j * 16 + cc;
                    int tok = tkl[ml];
                    atomicAdd(&out[(size_t)tok * H + col], acc[i][j][r] * wl[ml]);
                }
            }
}

extern "C" void kernel_launch(void* const* d_in, const int* in_sizes, int n_in,
                              void* d_out, int out_size, void* d_ws, size_t ws_size,
                              hipStream_t stream) {
    const float* x    = (const float*)d_in[0];
    const int*   vm   = (const int*)d_in[1];
    const float* tg   = (const float*)d_in[2];
    const float* twg  = (const float*)d_in[3];
    const float* twu  = (const float*)d_in[4];
    const float* twd  = (const float*)d_in[5];
    const float* ig   = (const float*)d_in[6];
    const float* iwg  = (const float*)d_in[7];
    const float* iwu  = (const float*)d_in[8];
    const float* iwd  = (const float*)d_in[9];
    const float* swg  = (const float*)d_in[10];
    const float* swu  = (const float*)d_in[11];
    const float* swd  = (const float*)d_in[12];
    float* out = (float*)d_out;
    char* ws = (char*)d_ws;

    bf16* xb     = (bf16*)(ws + OFF_XBF);
    int*  counts = (int*)(ws + OFF_CNT);
    int*  toks   = (int*)(ws + OFF_TOK);
    float* wtsp  = (float*)(ws + OFF_WTS);
    bf16* htxt   = (bf16*)(ws + OFF_HTXT);
    bf16* himg   = (bf16*)(ws + OFF_HIMG);
    bf16* hsh    = (bf16*)(ws + OFF_HSH);

    hipMemsetAsync(counts, 0, 128, stream);
    hipMemsetAsync(out, 0, (size_t)T * H * sizeof(float), stream);

    k_cast_init<<<dim3((T * H / 4) / 256), dim3(256), 0, stream>>>(x, xb, counts, toks, wtsp);
    k_router<<<dim3(T / 4), dim3(256), 0, stream>>>(x, vm, tg, ig, counts, toks, wtsp);

    // all gate+up GEMMs (text/image/shared) in ONE launch -> 4-5 active blocks/CU
    k_gateup_all<<<dim3(ISH / NT, CAP / MT, 17), dim3(256), 0, stream>>>(
        twg, twu, iwg, iwu, swg, swu, xb, counts, toks, htxt, himg, hsh);

    // all down GEMMs in ONE launch
    k_down_all<<<dim3(H / NT, CAP / MT, 17), dim3(256), 0, stream>>>(
        twd, iwd, swd, htxt, himg, hsh, counts, toks, wtsp, out);
}